// Round 4
// baseline (120.685 us; speedup 1.0000x reference)
//
#include <hip/hip_runtime.h>
#include <hip/hip_fp16.h>
#include <math.h>

#define LRES 2048
#define NB 8
#define KSEL 64
#define RCUT2 100.0f
#define EMBD 16
#define RROWS 8
#define ROWBLKS (LRES / RROWS)   // 256 blocks per batch
#define CANDCAP 128
#define SELCAP (RROWS * KSEL)    // 512; exact per-row bound is 64

// prep: per-residue rho + pack (x,y,z,rho) as half4 into ws
__global__ void prep_kernel(const float* __restrict__ R,
                            const int* __restrict__ seq,
                            const float* __restrict__ emb,
                            const float* __restrict__ w,
                            const float* __restrict__ bias,
                            uint2* __restrict__ pts) {
    int idx = blockIdx.x * blockDim.x + threadIdx.x;
    if (idx < NB * LRES) {
        int s = seq[idx];
        float x = bias[0];
#pragma unroll
        for (int d = 0; d < EMBD; ++d) x += emb[s * EMBD + d] * w[d];
        float rho = 1.6f + 1.2f / (1.0f + expf(-x));
        __half2 h0 = __floats2half2_rn(R[idx * 3 + 0], R[idx * 3 + 1]);
        __half2 h1 = __floats2half2_rn(R[idx * 3 + 2], rho);
        pts[idx] = make_uint2(*(unsigned*)&h0, *(unsigned*)&h1);
    }
}

__device__ __forceinline__ void decode_pt(uint2 u, float2& f0, float2& f1) {
    f0 = __half22float2(*(__half2*)&u.x);   // x, y
    f1 = __half22float2(*(__half2*)&u.y);   // z, rho
}

// one block per 8 consecutive rows; 256 threads; coords read straight from L1/L2
__global__ __launch_bounds__(256, 6) void repel_kernel(const uint2* __restrict__ pts,
                                                       float* __restrict__ partial) {
    const int blk = blockIdx.x;
    const int b = blk >> 8;                  // / 256
    const int i0 = (blk & 255) * RROWS;
    const int tid = threadIdx.x;

    __shared__ unsigned hist[RROWS * 256];   // 8 KB; aliased as sellist after scan
    __shared__ float2 cand[RROWS][CANDCAP];  // 8 KB
    __shared__ unsigned wsum[RROWS][4];
    __shared__ unsigned shT[RROWS], shm[RROWS], shn[RROWS];
    __shared__ unsigned sh_nsel;
    __shared__ float shredf[4];
    float2* sellist = (float2*)hist;         // 512 float2 = 4 KB <= 8 KB

    const uint2* __restrict__ P = pts + b * LRES;

#pragma unroll
    for (int r = 0; r < RROWS; ++r) hist[r * 256 + tid] = 0u;
    if (tid < RROWS) { shT[tid] = 256u; shm[tid] = 0u; shn[tid] = 0u; }
    if (tid == 0) sh_nsel = 0u;

    // centers
    float cx[RROWS], cy[RROWS], cz[RROWS], rhoi[RROWS];
#pragma unroll
    for (int r = 0; r < RROWS; ++r) {
        float2 f0, f1; decode_pt(P[i0 + r], f0, f1);
        cx[r] = f0.x; cy[r] = f0.y; cz[r] = f1.x; rhoi[r] = f1.y;
    }
    __syncthreads();

    // ---- pass 1: distances -> per-row histograms (bin monotone in d^2) ----
#pragma unroll
    for (int k = 0; k < 8; ++k) {
        int j = tid + (k << 8);
        float2 f0, f1; decode_pt(P[j], f0, f1);
        int base = j - i0;                   // dij = base - r
#pragma unroll
        for (int r = 0; r < RROWS; ++r) {
            float dx = f0.x - cx[r], dy = f0.y - cy[r], dz = f1.x - cz[r];
            float d2 = dx * dx + dy * dy + dz * dz;
            int dij = base - r; dij = (dij < 0) ? -dij : dij;
            if (dij <= 2) d2 = 1e30f;
            if (d2 < RCUT2) {
                unsigned bin = (unsigned)(d2 * 2.56f);
                atomicAdd(&hist[r * 256 + bin], 1u);
            }
        }
    }
    __syncthreads();

    // ---- inclusive scan of each row's histogram ----
    unsigned vv[RROWS], ss[RROWS];
#pragma unroll
    for (int r = 0; r < RROWS; ++r) {
        unsigned v = hist[r * 256 + tid];
        unsigned s = v;
#pragma unroll
        for (int o = 1; o < 64; o <<= 1) {
            unsigned u = __shfl_up(s, o, 64);
            if ((tid & 63) >= o) s += u;
        }
        if ((tid & 63) == 63) wsum[r][tid >> 6] = s;
        vv[r] = v; ss[r] = s;
    }
    __syncthreads();

    // ---- boundary bin T + within-bin rank m per row ----
#pragma unroll
    for (int r = 0; r < RROWS; ++r) {
        unsigned woff = 0;
#pragma unroll
        for (int w = 0; w < 3; ++w) if ((tid >> 6) > w) woff += wsum[r][w];
        unsigned S = ss[r] + woff;
        unsigned total = wsum[r][0] + wsum[r][1] + wsum[r][2] + wsum[r][3];
        if (total > KSEL && S >= KSEL && (S - vv[r]) < KSEL) {
            shT[r] = tid; shm[r] = KSEL - (S - vv[r]);
        }
        // total <= KSEL: shT stays 256 -> all in-cutoff pairs selected, no refinement
    }
    __syncthreads();

    unsigned Tr[RROWS];
#pragma unroll
    for (int r = 0; r < RROWS; ++r) Tr[r] = shT[r];

    // ---- pass 2: recompute distances; compact sure-selected; collect boundary bin ----
#pragma unroll
    for (int k = 0; k < 8; ++k) {
        int j = tid + (k << 8);
        float2 f0, f1; decode_pt(P[j], f0, f1);
        int base = j - i0;
#pragma unroll
        for (int r = 0; r < RROWS; ++r) {
            float dx = f0.x - cx[r], dy = f0.y - cy[r], dz = f1.x - cz[r];
            float d2 = dx * dx + dy * dy + dz * dz;
            int dij = base - r; dij = (dij < 0) ? -dij : dij;
            if (dij <= 2) d2 = 1e30f;
            if (d2 < RCUT2) {
                unsigned bin = (unsigned)(d2 * 2.56f);
                if (bin < Tr[r]) {
                    unsigned p = atomicAdd(&sh_nsel, 1u);
                    if (p < SELCAP) sellist[p] = make_float2(d2, rhoi[r] + f1.y);
                } else if (bin == Tr[r]) {
                    unsigned p = atomicAdd(&shn[r], 1u);
                    if (p < CANDCAP) cand[r][p] = make_float2(d2, rhoi[r] + f1.y);
                }
            }
        }
    }
    __syncthreads();

    // ---- exact rank-select within each boundary bin; append the m smallest ----
#pragma unroll
    for (int r = 0; r < RROWS; ++r) {
        unsigned n = shn[r]; if (n > CANDCAP) n = CANDCAP;
        unsigned m = shm[r];
        for (unsigned c = tid; c < n; c += 256) {
            float key = cand[r][c].x;
            unsigned rank = 0;
            for (unsigned q = 0; q < n; ++q) {
                float kq = cand[r][q].x;
                rank += (kq < key || (kq == key && q < c)) ? 1u : 0u;
            }
            if (rank < m) {
                unsigned p = atomicAdd(&sh_nsel, 1u);
                if (p < SELCAP) sellist[p] = cand[r][c];
            }
        }
    }
    __syncthreads();

    // ---- dense evaluation + block reduce ----
    float acc = 0.0f;
    unsigned nsel = sh_nsel; if (nsel > SELCAP) nsel = SELCAP;
    for (unsigned idx = tid; idx < nsel; idx += 256) {
        float2 it = sellist[idx];
        float r = __fsqrt_rn(fmaxf(it.x, 1e-12f));
        float x = (it.y - r) * (1.0f / 0.3f);
        float sp = fmaxf(x, 0.0f) + __logf(1.0f + __expf(-fabsf(x)));
        float t = (r - 8.0f) * 0.5f;
        t = fminf(fmaxf(t, 0.0f), 1.0f);
        float sw = 1.0f - t * t * (3.0f - 2.0f * t);
        acc += 10.0f * sp * sw;
    }
#pragma unroll
    for (int o = 32; o > 0; o >>= 1) acc += __shfl_down(acc, o, 64);
    if ((tid & 63) == 0) shredf[tid >> 6] = acc;
    __syncthreads();
    if (tid == 0) partial[blk] = shredf[0] + shredf[1] + shredf[2] + shredf[3];
}

// out[b] = sum of 256 partials
__global__ void reduce_kernel(const float* __restrict__ partial, float* __restrict__ out) {
    __shared__ float sh[4];
    const int b = blockIdx.x;
    const int tid = threadIdx.x;
    float acc = partial[b * ROWBLKS + tid];
#pragma unroll
    for (int o = 32; o > 0; o >>= 1) acc += __shfl_down(acc, o, 64);
    if ((tid & 63) == 0) sh[tid >> 6] = acc;
    __syncthreads();
    if (tid == 0) out[b] = sh[0] + sh[1] + sh[2] + sh[3];
}

extern "C" void kernel_launch(void* const* d_in, const int* in_sizes, int n_in,
                              void* d_out, int out_size, void* d_ws, size_t ws_size,
                              hipStream_t stream) {
    const float* R    = (const float*)d_in[0];   // (8, 2048, 3) f32
    const int*   seq  = (const int*)d_in[1];     // (8, 2048) int
    const float* emb  = (const float*)d_in[2];   // (20, 16) f32
    const float* w    = (const float*)d_in[3];   // (1, 16) f32
    const float* bias = (const float*)d_in[4];   // (1,) f32
    float* out = (float*)d_out;                  // (8,) f32

    uint2* pts     = (uint2*)d_ws;                         // 16384 * 8 B
    float* partial = (float*)((char*)d_ws + NB * LRES * sizeof(uint2));  // 2048 floats

    prep_kernel<<<(NB * LRES + 255) / 256, 256, 0, stream>>>(R, seq, emb, w, bias, pts);
    repel_kernel<<<NB * ROWBLKS, 256, 0, stream>>>(pts, partial);
    reduce_kernel<<<NB, 256, 0, stream>>>(partial, out);
}

// Round 5
// 118.470 us; speedup vs baseline: 1.0187x; 1.0187x over previous
//
#include <hip/hip_runtime.h>
#include <hip/hip_fp16.h>
#include <math.h>

#define LRES 2048
#define NB 8
#define KSEL 64
#define EMBD 16
#define KMAX 0x42C7FFFFu   // largest float bits < 100.0f (= RCUT^2)
#define ITEMCAP 96         // 64 + tie slack

// prep: per-residue rho + pack (x,y,z,rho) as half4 into ws
__global__ void prep_kernel(const float* __restrict__ R,
                            const int* __restrict__ seq,
                            const float* __restrict__ emb,
                            const float* __restrict__ w,
                            const float* __restrict__ bias,
                            uint2* __restrict__ pts) {
    int idx = blockIdx.x * blockDim.x + threadIdx.x;
    if (idx < NB * LRES) {
        int s = seq[idx];
        float x = bias[0];
#pragma unroll
        for (int d = 0; d < EMBD; ++d) x += emb[s * EMBD + d] * w[d];
        float rho = 1.6f + 1.2f / (1.0f + expf(-x));
        __half2 h0 = __floats2half2_rn(R[idx * 3 + 0], R[idx * 3 + 1]);
        __half2 h1 = __floats2half2_rn(R[idx * 3 + 2], rho);
        pts[idx] = make_uint2(*(unsigned*)&h0, *(unsigned*)&h1);
    }
}

__device__ __forceinline__ void decode_pt(uint2 u, float2& f0, float2& f1) {
    f0 = __half22float2(*(__half2*)&u.x);   // x, y
    f1 = __half22float2(*(__half2*)&u.y);   // z, rho
}

// one WAVE per row; 4 waves (rows) per block; no __syncthreads anywhere
__global__ __launch_bounds__(256) void repel_kernel(const uint2* __restrict__ pts,
                                                    float* __restrict__ partial) {
    const int w    = threadIdx.x >> 6;
    const int lane = threadIdx.x & 63;
    const int row  = blockIdx.x * 4 + w;
    const int b    = row >> 11;
    const int i    = row & 2047;

    __shared__ unsigned scnt[4];
    __shared__ uint2 items[4][ITEMCAP];
    if (lane == 0) scnt[w] = 0u;

    const uint2* __restrict__ P = pts + (b << 11);
    const uint4* __restrict__ P4 = (const uint4*)P;

    float2 c0, c1; decode_pt(P[i], c0, c1);
    const float cx = c0.x, cy = c0.y, cz = c1.x, rho_i = c1.y;

    // ---- distances: lane owns 32 j's, loaded 2-at-a-time via dwordx4 ----
    unsigned d2u[32];
#pragma unroll
    for (int t = 0; t < 16; ++t) {
        uint4 u = P4[(t << 6) + lane];              // points j0, j0+1
        int j0 = (t << 7) + (lane << 1);
        {
            float2 f0 = __half22float2(*(__half2*)&u.x);
            float2 f1 = __half22float2(*(__half2*)&u.y);
            float dx = f0.x - cx, dy = f0.y - cy, dz = f1.x - cz;
            float d2 = dx * dx + dy * dy + dz * dz;
            int dij = j0 - i; dij = (dij < 0) ? -dij : dij;
            d2u[2 * t] = (dij <= 2) ? 0xFFFFFFFFu : __float_as_uint(d2);
        }
        {
            float2 f0 = __half22float2(*(__half2*)&u.z);
            float2 f1 = __half22float2(*(__half2*)&u.w);
            float dx = f0.x - cx, dy = f0.y - cy, dz = f1.x - cz;
            float d2 = dx * dx + dy * dy + dz * dz;
            int dij = j0 + 1 - i; dij = (dij < 0) ? -dij : dij;
            d2u[2 * t + 1] = (dij <= 2) ? 0xFFFFFFFFu : __float_as_uint(d2);
        }
    }

    // ---- wave-wide count via ballot+popcount (scalar pipe, no shuffles) ----
#define WCOUNT(key, cvar)                                          \
    {                                                              \
        int _c = 0;                                                \
        _Pragma("unroll")                                          \
        for (int m = 0; m < 32; ++m)                               \
            _c += __popcll(__ballot(d2u[m] <= (key)));             \
        (cvar) = _c;                                               \
    }

    unsigned tkey = KMAX;       // d2u <= KMAX  <=>  d2 < 100.0
    int c;
    WCOUNT(KMAX, c)
    if (c > KSEL) {
        // bisect smallest u with count(<=u) >= 64 (exact, bit-monotone)
        unsigned lo = 0u, hi = KMAX;
        while (lo < hi) {
            unsigned mid = (lo + hi) >> 1;
            int cc;
            WCOUNT(mid, cc)
            if (cc == KSEL) { lo = mid; break; }
            if (cc > KSEL) hi = mid; else lo = mid + 1u;
        }
        tkey = lo;
    }

    // ---- compact selected (d2, j) into per-wave LDS list (same-wave: no barrier) ----
#pragma unroll
    for (int m = 0; m < 32; ++m) {
        if (d2u[m] <= tkey) {
            unsigned j = ((unsigned)(m >> 1) << 7) + ((unsigned)lane << 1) + (unsigned)(m & 1);
            unsigned pos = atomicAdd(&scnt[w], 1u);
            if (pos < ITEMCAP) items[w][pos] = make_uint2(d2u[m], j);
        }
    }

    // ---- dense evaluation: <=96 items, <=2 per lane ----
    unsigned n = scnt[w]; if (n > ITEMCAP) n = ITEMCAP;
    float acc = 0.0f;
    for (unsigned idx = lane; idx < n; idx += 64) {
        uint2 it = items[w][idx];
        float d2 = __uint_as_float(it.x);
        float r = __fsqrt_rn(fmaxf(d2, 1e-12f));
        float2 f0, f1; decode_pt(P[it.y], f0, f1);
        float x = (rho_i + f1.y - r) * (1.0f / 0.3f);
        float sp = fmaxf(x, 0.0f) + __logf(1.0f + __expf(-fabsf(x)));
        float t = fminf(fmaxf((r - 8.0f) * 0.5f, 0.0f), 1.0f);
        float sw = 1.0f - t * t * (3.0f - 2.0f * t);
        acc += 10.0f * sp * sw;
    }
#pragma unroll
    for (int o = 32; o > 0; o >>= 1) acc += __shfl_down(acc, o, 64);
    if (lane == 0) partial[row] = acc;
}

// out[b] = sum of 2048 per-row partials
__global__ void reduce_kernel(const float* __restrict__ partial, float* __restrict__ out) {
    __shared__ float sh[4];
    const int b = blockIdx.x;
    const int tid = threadIdx.x;
    float acc = 0.0f;
#pragma unroll
    for (int k = 0; k < 8; ++k) acc += partial[(b << 11) + (k << 8) + tid];
#pragma unroll
    for (int o = 32; o > 0; o >>= 1) acc += __shfl_down(acc, o, 64);
    if ((tid & 63) == 0) sh[tid >> 6] = acc;
    __syncthreads();
    if (tid == 0) out[b] = sh[0] + sh[1] + sh[2] + sh[3];
}

extern "C" void kernel_launch(void* const* d_in, const int* in_sizes, int n_in,
                              void* d_out, int out_size, void* d_ws, size_t ws_size,
                              hipStream_t stream) {
    const float* R    = (const float*)d_in[0];   // (8, 2048, 3) f32
    const int*   seq  = (const int*)d_in[1];     // (8, 2048) int
    const float* emb  = (const float*)d_in[2];   // (20, 16) f32
    const float* w    = (const float*)d_in[3];   // (1, 16) f32
    const float* bias = (const float*)d_in[4];   // (1,) f32
    float* out = (float*)d_out;                  // (8,) f32

    uint2* pts     = (uint2*)d_ws;                                       // 128 KB
    float* partial = (float*)((char*)d_ws + NB * LRES * sizeof(uint2));  // 64 KB

    prep_kernel<<<(NB * LRES + 255) / 256, 256, 0, stream>>>(R, seq, emb, w, bias, pts);
    repel_kernel<<<NB * LRES / 4, 256, 0, stream>>>(pts, partial);
    reduce_kernel<<<NB, 256, 0, stream>>>(partial, out);
}

// Round 6
// 98.783 us; speedup vs baseline: 1.2217x; 1.1993x over previous
//
#include <hip/hip_runtime.h>
#include <hip/hip_fp16.h>
#include <math.h>

#define LRES 2048
#define NB 8
#define KSEL 64
#define EMBD 16
#define KMAX 0x42C7FFFFu   // largest float bits < 100.0f (= RCUT^2)
#define CANDCAP 96
#define ITEMCAP 96

// prep: per-residue rho + pack (x,y,z,rho) as half4 into ws
__global__ void prep_kernel(const float* __restrict__ R,
                            const int* __restrict__ seq,
                            const float* __restrict__ emb,
                            const float* __restrict__ w,
                            const float* __restrict__ bias,
                            uint2* __restrict__ pts) {
    int idx = blockIdx.x * blockDim.x + threadIdx.x;
    if (idx < NB * LRES) {
        int s = seq[idx];
        float x = bias[0];
#pragma unroll
        for (int d = 0; d < EMBD; ++d) x += emb[s * EMBD + d] * w[d];
        float rho = 1.6f + 1.2f / (1.0f + expf(-x));
        __half2 h0 = __floats2half2_rn(R[idx * 3 + 0], R[idx * 3 + 1]);
        __half2 h1 = __floats2half2_rn(R[idx * 3 + 2], rho);
        pts[idx] = make_uint2(*(unsigned*)&h0, *(unsigned*)&h1);
    }
}

__device__ __forceinline__ void decode_pt(uint2 u, float2& f0, float2& f1) {
    f0 = __half22float2(*(__half2*)&u.x);   // x, y
    f1 = __half22float2(*(__half2*)&u.y);   // z, rho
}

__device__ __forceinline__ unsigned lane_prefix(unsigned long long m) {
    return __builtin_amdgcn_mbcnt_hi((unsigned)(m >> 32),
                                     __builtin_amdgcn_mbcnt_lo((unsigned)m, 0u));
}

#define LDS_FENCE() asm volatile("s_waitcnt lgkmcnt(0)" ::: "memory")

// one WAVE per row; 4 waves per block; no __syncthreads anywhere
__global__ __launch_bounds__(256, 6) void repel_kernel(const uint2* __restrict__ pts,
                                                       float* __restrict__ partial) {
    const int w    = threadIdx.x >> 6;
    const int lane = threadIdx.x & 63;
    const int row  = blockIdx.x * 4 + w;
    const int b    = row >> 11;
    const int i    = row & 2047;

    __shared__ unsigned hist[4][256];    // 4 KB; per-wave; aliased as items later
    __shared__ unsigned cand[4][CANDCAP];
    __shared__ unsigned shT[4], shm[4], shtk[4];
    uint2* items = (uint2*)&hist[w][0];  // 96*8 = 768 B <= 1024 B

    const uint2* __restrict__ P = pts + (b << 11);
    const uint4* __restrict__ P4 = (const uint4*)P;

    // zero own wave's histogram (4 bins/lane, one b128 store)
    *(uint4*)&hist[w][lane << 2] = make_uint4(0u, 0u, 0u, 0u);

    float2 c0, c1; decode_pt(P[i], c0, c1);
    const float cx = c0.x, cy = c0.y, cz = c1.x, rho_i = c1.y;

    // ---- distances: lane owns 32 j's via 16 dwordx4 loads ----
    unsigned d2u[32];
#pragma unroll
    for (int t = 0; t < 16; ++t) {
        uint4 u = P4[(t << 6) + lane];               // points j0, j0+1
        int j0 = (t << 7) + (lane << 1);
        {
            float2 f0 = __half22float2(*(__half2*)&u.x);
            float2 f1 = __half22float2(*(__half2*)&u.y);
            float dx = f0.x - cx, dy = f0.y - cy, dz = f1.x - cz;
            float d2 = dx * dx + dy * dy + dz * dz;
            int dij = j0 - i; dij = (dij < 0) ? -dij : dij;
            d2u[2 * t] = (dij <= 2) ? 0xFFFFFFFFu : __float_as_uint(d2);
        }
        {
            float2 f0 = __half22float2(*(__half2*)&u.z);
            float2 f1 = __half22float2(*(__half2*)&u.w);
            float dx = f0.x - cx, dy = f0.y - cy, dz = f1.x - cz;
            float d2 = dx * dx + dy * dy + dz * dz;
            int dij = j0 + 1 - i; dij = (dij < 0) ? -dij : dij;
            d2u[2 * t + 1] = (dij <= 2) ? 0xFFFFFFFFu : __float_as_uint(d2);
        }
    }
    LDS_FENCE();   // hist zeroing complete before atomics

    // ---- per-wave histogram: fire-and-forget ds_add (no return, no chain) ----
#pragma unroll
    for (int m = 0; m < 32; ++m) {
        if (d2u[m] <= KMAX) {
            unsigned bin = (unsigned)(__uint_as_float(d2u[m]) * 2.56f);
            atomicAdd(&hist[w][bin], 1u);
        }
    }
    LDS_FENCE();

    // ---- one-time scan: lane reads 4 bins, 64-lane inclusive scan of lane sums ----
    uint4 hv = *(const uint4*)&hist[w][lane << 2];
    unsigned p = hv.x + hv.y + hv.z + hv.w;
    unsigned s = p;
#pragma unroll
    for (int o = 1; o < 64; o <<= 1) {
        unsigned u = __shfl_up(s, o, 64);
        if (lane >= o) s += u;
    }
    unsigned total = __builtin_amdgcn_readfirstlane(__shfl(s, 63, 64));

    unsigned tkeyu = KMAX;           // total<=64: select every in-cutoff pair
    if (total > KSEL) {
        // boundary bin T (cum crosses 64) + within-bin rank m
        unsigned e0 = s - p;
        unsigned e1 = e0 + hv.x, e2 = e1 + hv.y, e3 = e2 + hv.z, e4 = e3 + hv.w;
        if (e1 >= KSEL && e0 < KSEL)      { shT[w] = (lane << 2) + 0; shm[w] = KSEL - e0; }
        else if (e2 >= KSEL && e1 < KSEL) { shT[w] = (lane << 2) + 1; shm[w] = KSEL - e1; }
        else if (e3 >= KSEL && e2 < KSEL) { shT[w] = (lane << 2) + 2; shm[w] = KSEL - e2; }
        else if (e4 >= KSEL && e3 < KSEL) { shT[w] = (lane << 2) + 3; shm[w] = KSEL - e3; }
        LDS_FENCE();
        const unsigned T  = __builtin_amdgcn_readfirstlane(shT[w]);
        const unsigned mm = __builtin_amdgcn_readfirstlane(shm[w]);

        // collect boundary-bin candidates via ballot+mbcnt (fire-and-forget writes)
        unsigned n = 0;
#pragma unroll
        for (int m = 0; m < 32; ++m) {
            bool pr = false;
            if (d2u[m] <= KMAX)
                pr = ((unsigned)(__uint_as_float(d2u[m]) * 2.56f) == T);
            unsigned long long mask = __ballot(pr);
            if (pr) {
                unsigned pos = n + lane_prefix(mask);
                if (pos < CANDCAP) cand[w][pos] = d2u[m];
            }
            n += (unsigned)__popcll(mask);
        }
        LDS_FENCE();
        if (n > CANDCAP) n = CANDCAP;
        // exact mm-th smallest among n candidates (n >= mm by construction)
        for (unsigned c = lane; c < n; c += 64) {
            unsigned key = cand[w][c];
            unsigned rank = 0;
            for (unsigned q = 0; q < n; ++q) {
                unsigned kq = cand[w][q];
                rank += (kq < key || (kq == key && q < c)) ? 1u : 0u;
            }
            if (rank == mm - 1) shtk[w] = key;
        }
        LDS_FENCE();
        tkeyu = __builtin_amdgcn_readfirstlane(shtk[w]);
    }

    // ---- compact selected (d2,j) via ballot+mbcnt into per-wave items ----
    unsigned base = 0;
#pragma unroll
    for (int m = 0; m < 32; ++m) {
        bool sel = (d2u[m] <= tkeyu);
        unsigned long long mask = __ballot(sel);
        if (sel) {
            unsigned pos = base + lane_prefix(mask);
            unsigned j = ((unsigned)(m >> 1) << 7) + ((unsigned)lane << 1) + (unsigned)(m & 1);
            if (pos < ITEMCAP) items[pos] = make_uint2(d2u[m], j);
        }
        base += (unsigned)__popcll(mask);
    }
    LDS_FENCE();

    // ---- dense evaluation (<=96 items, <=2 per lane) + wave reduce ----
    unsigned nsel = base; if (nsel > ITEMCAP) nsel = ITEMCAP;
    float acc = 0.0f;
    for (unsigned idx = lane; idx < nsel; idx += 64) {
        uint2 it = items[idx];
        float d2 = __uint_as_float(it.x);
        float r = __fsqrt_rn(fmaxf(d2, 1e-12f));
        float2 f0, f1; decode_pt(P[it.y], f0, f1);
        float x = (rho_i + f1.y - r) * (1.0f / 0.3f);
        float sp = fmaxf(x, 0.0f) + __logf(1.0f + __expf(-fabsf(x)));
        float t = fminf(fmaxf((r - 8.0f) * 0.5f, 0.0f), 1.0f);
        float sw = 1.0f - t * t * (3.0f - 2.0f * t);
        acc += 10.0f * sp * sw;
    }
#pragma unroll
    for (int o = 32; o > 0; o >>= 1) acc += __shfl_down(acc, o, 64);
    if (lane == 0) partial[row] = acc;
}

// out[b] = sum of 2048 per-row partials
__global__ void reduce_kernel(const float* __restrict__ partial, float* __restrict__ out) {
    __shared__ float sh[4];
    const int b = blockIdx.x;
    const int tid = threadIdx.x;
    float acc = 0.0f;
#pragma unroll
    for (int k = 0; k < 8; ++k) acc += partial[(b << 11) + (k << 8) + tid];
#pragma unroll
    for (int o = 32; o > 0; o >>= 1) acc += __shfl_down(acc, o, 64);
    if ((tid & 63) == 0) sh[tid >> 6] = acc;
    __syncthreads();
    if (tid == 0) out[b] = sh[0] + sh[1] + sh[2] + sh[3];
}

extern "C" void kernel_launch(void* const* d_in, const int* in_sizes, int n_in,
                              void* d_out, int out_size, void* d_ws, size_t ws_size,
                              hipStream_t stream) {
    const float* R    = (const float*)d_in[0];   // (8, 2048, 3) f32
    const int*   seq  = (const int*)d_in[1];     // (8, 2048) int
    const float* emb  = (const float*)d_in[2];   // (20, 16) f32
    const float* w    = (const float*)d_in[3];   // (1, 16) f32
    const float* bias = (const float*)d_in[4];   // (1,) f32
    float* out = (float*)d_out;                  // (8,) f32

    uint2* pts     = (uint2*)d_ws;                                       // 128 KB
    float* partial = (float*)((char*)d_ws + NB * LRES * sizeof(uint2));  // 64 KB

    prep_kernel<<<(NB * LRES + 255) / 256, 256, 0, stream>>>(R, seq, emb, w, bias, pts);
    repel_kernel<<<NB * LRES / 4, 256, 0, stream>>>(pts, partial);
    reduce_kernel<<<NB, 256, 0, stream>>>(partial, out);
}

// Round 7
// 89.543 us; speedup vs baseline: 1.3478x; 1.1032x over previous
//
#include <hip/hip_runtime.h>
#include <hip/hip_fp16.h>
#include <math.h>

#define LRES 2048
#define NB 8
#define KSEL 64
#define EMBD 16
#define NBIN 128
#define BINSCALE 1.28f          // bin = trunc(d2 * 1.28), d2 < 100 -> bin < 128
#define BINW 0.78125f           // 100/128, upper edge = (T+1)*BINW
#define NSLOT 16                // per-lane slot cap (Poisson(1) tail: P(>16) ~ 1e-14)

// prep: per-residue rho + pack (x,y,z,rho) as half4 into ws
__global__ void prep_kernel(const float* __restrict__ R,
                            const int* __restrict__ seq,
                            const float* __restrict__ emb,
                            const float* __restrict__ w,
                            const float* __restrict__ bias,
                            uint2* __restrict__ pts) {
    int idx = blockIdx.x * blockDim.x + threadIdx.x;
    if (idx < NB * LRES) {
        int s = seq[idx];
        float x = bias[0];
#pragma unroll
        for (int d = 0; d < EMBD; ++d) x += emb[s * EMBD + d] * w[d];
        float rho = 1.6f + 1.2f / (1.0f + expf(-x));
        __half2 h0 = __floats2half2_rn(R[idx * 3 + 0], R[idx * 3 + 1]);
        __half2 h1 = __floats2half2_rn(R[idx * 3 + 2], rho);
        pts[idx] = make_uint2(*(unsigned*)&h0, *(unsigned*)&h1);
    }
}

#define LDS_FENCE() asm volatile("s_waitcnt lgkmcnt(0)" ::: "memory")

// one WAVE per row; 4 independent waves per block; no __syncthreads
__global__ __launch_bounds__(256) void repel_kernel(const uint2* __restrict__ pts,
                                                    float* __restrict__ partial) {
    const int w    = threadIdx.x >> 6;
    const int lane = threadIdx.x & 63;
    const int row  = blockIdx.x * 4 + w;
    const int b    = row >> 11;
    const int i    = row & 2047;

    __shared__ unsigned hist[4][NBIN];            // 2 KB
    __shared__ unsigned slots[4][NSLOT][64];      // 16 KB; [slot][lane]: bank = lane&31
    __shared__ unsigned shT[4];

    const uint2* __restrict__ P = pts + (b << 11);
    const uint4* __restrict__ P4 = (const uint4*)P;

    // zero own wave's histogram (2 bins/lane) + default T = NBIN-1 (select all in-cutoff)
    *(uint2*)&hist[w][lane << 1] = make_uint2(0u, 0u);
    if (lane == 0) shT[w] = NBIN - 1;

    float2 cc0 = __half22float2(*(__half2*)&P[i].x);
    float2 cc1 = __half22float2(*(__half2*)&P[i].y);
    const float cx = cc0.x, cy = cc0.y, cz = cc1.x, rho_i = cc1.y;
    LDS_FENCE();   // zero-init complete before atomics

    // ---- pass 1: distances (lane owns 32 j's) + fused per-wave histogram ----
    unsigned d2u[32];
#pragma unroll
    for (int t = 0; t < 16; ++t) {
        uint4 u = P4[(t << 6) + lane];               // points j0, j0+1
        int j0 = (t << 7) + (lane << 1);
        {
            float2 f0 = __half22float2(*(__half2*)&u.x);
            float2 f1 = __half22float2(*(__half2*)&u.y);
            float dx = f0.x - cx, dy = f0.y - cy, dz = f1.x - cz;
            float d2 = dx * dx + dy * dy + dz * dz;
            int dij = j0 - i; dij = (dij < 0) ? -dij : dij;
            unsigned du = (dij <= 2) ? 0xFFFFFFFFu : __float_as_uint(d2);
            d2u[2 * t] = du;
            if (du <= 0x42C7FFFFu)                   // d2 < 100.0
                atomicAdd(&hist[w][(unsigned)(d2 * BINSCALE)], 1u);
        }
        {
            float2 f0 = __half22float2(*(__half2*)&u.z);
            float2 f1 = __half22float2(*(__half2*)&u.w);
            float dx = f0.x - cx, dy = f0.y - cy, dz = f1.x - cz;
            float d2 = dx * dx + dy * dy + dz * dz;
            int dij = j0 + 1 - i; dij = (dij < 0) ? -dij : dij;
            unsigned du = (dij <= 2) ? 0xFFFFFFFFu : __float_as_uint(d2);
            d2u[2 * t + 1] = du;
            if (du <= 0x42C7FFFFu)
                atomicAdd(&hist[w][(unsigned)(d2 * BINSCALE)], 1u);
        }
    }
    LDS_FENCE();

    // ---- scan: lane holds 2 bins; 64-lane inclusive scan; crossing lane sets T ----
    uint2 hv = *(const uint2*)&hist[w][lane << 1];
    unsigned p = hv.x + hv.y;
    unsigned s = p;
#pragma unroll
    for (int o = 1; o < 64; o <<= 1) {
        unsigned u = __shfl_up(s, o, 64);
        if (lane >= o) s += u;
    }
    unsigned e0 = s - p;
    if (s >= KSEL && e0 < KSEL) {                    // unique crossing lane (if total >= 64)
        unsigned sub = (e0 + hv.x >= KSEL) ? 0u : 1u;
        shT[w] = (lane << 1) + sub;                  // whole boundary bin selected
    }
    LDS_FENCE();
    const unsigned T = shT[w];                       // wave-uniform broadcast read
    const unsigned tkb = __float_as_uint((float)(T + 1) * BINW);  // select iff bits(d2) < tkb

    // ---- capture: each lane writes its selected (d2|j) to private slots ----
    unsigned cnt = 0;
#pragma unroll
    for (int m = 0; m < 32; ++m) {
        if (d2u[m] < tkb && cnt < NSLOT) {
            unsigned j = (unsigned)(((m >> 1) << 7) | (m & 1)) + ((unsigned)lane << 1);
            slots[w][cnt][lane] = (d2u[m] & 0xFFFFF800u) | j;   // j < 2048 fits low 11 bits
            ++cnt;
        }
    }
    LDS_FENCE();

    // ---- eval own slots (wave runs max-cnt ~4 iterations) + wave reduce ----
    float acc = 0.0f;
    for (unsigned k = 0; k < cnt; ++k) {
        unsigned key = slots[w][k][lane];
        unsigned j = key & 2047u;
        float d2 = __uint_as_float(key & 0xFFFFF800u);
        float r = __fsqrt_rn(fmaxf(d2, 1e-12f));
        uint2 pj = P[j];
        float rho_j = __high2float(*(__half2*)&pj.y);
        float x = (rho_i + rho_j - r) * (1.0f / 0.3f);
        float sp = fmaxf(x, 0.0f) + __logf(1.0f + __expf(-fabsf(x)));
        float t = fminf(fmaxf((r - 8.0f) * 0.5f, 0.0f), 1.0f);
        float sw = 1.0f - t * t * (3.0f - 2.0f * t);
        acc += 10.0f * sp * sw;
    }
#pragma unroll
    for (int o = 32; o > 0; o >>= 1) acc += __shfl_down(acc, o, 64);
    if (lane == 0) partial[row] = acc;
}

// out[b] = sum of 2048 per-row partials
__global__ void reduce_kernel(const float* __restrict__ partial, float* __restrict__ out) {
    __shared__ float sh[4];
    const int b = blockIdx.x;
    const int tid = threadIdx.x;
    float acc = 0.0f;
#pragma unroll
    for (int k = 0; k < 8; ++k) acc += partial[(b << 11) + (k << 8) + tid];
#pragma unroll
    for (int o = 32; o > 0; o >>= 1) acc += __shfl_down(acc, o, 64);
    if ((tid & 63) == 0) sh[tid >> 6] = acc;
    __syncthreads();
    if (tid == 0) out[b] = sh[0] + sh[1] + sh[2] + sh[3];
}

extern "C" void kernel_launch(void* const* d_in, const int* in_sizes, int n_in,
                              void* d_out, int out_size, void* d_ws, size_t ws_size,
                              hipStream_t stream) {
    const float* R    = (const float*)d_in[0];   // (8, 2048, 3) f32
    const int*   seq  = (const int*)d_in[1];     // (8, 2048) int
    const float* emb  = (const float*)d_in[2];   // (20, 16) f32
    const float* w    = (const float*)d_in[3];   // (1, 16) f32
    const float* bias = (const float*)d_in[4];   // (1,) f32
    float* out = (float*)d_out;                  // (8,) f32

    uint2* pts     = (uint2*)d_ws;                                       // 128 KB
    float* partial = (float*)((char*)d_ws + NB * LRES * sizeof(uint2));  // 64 KB

    prep_kernel<<<(NB * LRES + 255) / 256, 256, 0, stream>>>(R, seq, emb, w, bias, pts);
    repel_kernel<<<NB * LRES / 4, 256, 0, stream>>>(pts, partial);
    reduce_kernel<<<NB, 256, 0, stream>>>(partial, out);
}